// Round 1
// baseline (83.094 us; speedup 1.0000x reference)
//
#include <hip/hip_runtime.h>

// LengthRegulator: out[b, t, :] = phoneme[b, idx[b,t], :]
// where idx[b,t] = searchsorted(cumsum(durations[b]), t, side='right').
// Shapes fixed by the harness: B=16, N=256, D=512, T=2048. fp32 in/out.

constexpr int B = 16;
constexpr int N = 256;   // tokens per batch (== block size)
constexpr int D = 512;   // feature dim -> 128 float4 per row
constexpr int T = 2048;  // output frames per batch

constexpr int BLOCKS_PER_B = 128;                 // blocks per batch element
constexpr int FRAMES_PER_BLOCK = T / BLOCKS_PER_B; // 16 frames per block
constexpr int VEC_PER_ROW = D / 4;                 // 128 float4 per row

__global__ __launch_bounds__(256) void lenreg_kernel(
    const float* __restrict__ phoneme,   // (B, N, D)
    const int*   __restrict__ durations, // (B, N)
    float*       __restrict__ out)       // (B, T, D)
{
    __shared__ int ends[N];                 // inclusive cumsum of durations
    __shared__ int fidx[FRAMES_PER_BLOCK];  // token index per frame in this chunk

    const int b     = blockIdx.x / BLOCKS_PER_B;
    const int chunk = blockIdx.x % BLOCKS_PER_B;
    const int tid   = threadIdx.x;

    // --- (a) inclusive prefix sum of durations[b, :] (N == blockDim.x == 256)
    ends[tid] = durations[b * N + tid];
    __syncthreads();
    #pragma unroll
    for (int off = 1; off < N; off <<= 1) {
        int v = 0;
        if (tid >= off) v = ends[tid - off];
        __syncthreads();
        if (tid >= off) ends[tid] += v;
        __syncthreads();
    }

    // --- (b) token index for each frame in this block's chunk
    const int f0 = chunk * FRAMES_PER_BLOCK;
    if (tid < FRAMES_PER_BLOCK) {
        const int t = f0 + tid;
        // first n with ends[n] > t  (searchsorted side='right' on inclusive cumsum)
        int lo = 0, hi = N;
        while (lo < hi) {
            const int mid = (lo + hi) >> 1;
            if (ends[mid] > t) hi = mid; else lo = mid + 1;
        }
        fidx[tid] = (lo < N - 1) ? lo : (N - 1);
    }
    __syncthreads();

    // --- (c) stream rows: 2 rows per iteration (128 float4 lanes per row)
    const float4* __restrict__ ph4  = (const float4*)phoneme;
    float4*       __restrict__ out4 = (float4*)out;

    const int lane = tid & (VEC_PER_ROW - 1);   // 0..127
    const int half = tid >> 7;                  // 0 or 1
    #pragma unroll
    for (int i = 0; i < FRAMES_PER_BLOCK / 2; ++i) {
        const int r     = i * 2 + half;         // frame within chunk, 0..15
        const int token = fidx[r];
        const long src  = ((long)(b * N + token)) * VEC_PER_ROW + lane;
        const long dst  = ((long)b * T + (f0 + r)) * VEC_PER_ROW + lane;
        out4[dst] = ph4[src];
    }
}

extern "C" void kernel_launch(void* const* d_in, const int* in_sizes, int n_in,
                              void* d_out, int out_size, void* d_ws, size_t ws_size,
                              hipStream_t stream) {
    const float* phoneme   = (const float*)d_in[0];
    const int*   durations = (const int*)d_in[1];
    // d_in[2] is total_len == T (compile-time constant here)
    float* out = (float*)d_out;

    lenreg_kernel<<<B * BLOCKS_PER_B, 256, 0, stream>>>(phoneme, durations, out);
}